// Round 9
// baseline (183.793 us; speedup 1.0000x reference)
//
#include <hip/hip_runtime.h>

#define BB 64
#define CC 512
#define NPIX 784
#define KK 32
#define NSA 13          // kA: 13 splits of 64 px (split 12 overlaps: p0=720)
#define AS 800          // A row stride in shorts (784 padded to 25*32)
#define CW_S 520        // cw LDS row stride (shorts): 260 dw == 4 mod 32 -> conflict-free b128
#define NSTEP 24        // kB full 32-wide n-steps (24*32 = 768), +1 predicated tail

typedef __attribute__((ext_vector_type(8))) short short8;
typedef __attribute__((ext_vector_type(4))) float floatx4;
typedef __attribute__((ext_vector_type(4))) unsigned short ushort4v;

// workspace layout: A bf16 [64][32][800] (3.28 MB), then wsum_p fp32 [13][64][32]
#define WSUM_OFF (BB * KK * AS)   // in shorts; byte offset 6553600 (16-aligned)

__device__ __forceinline__ unsigned short f2bf(float f) {
    union { float f; unsigned u; } v; v.f = f;
    return (unsigned short)((v.u + 0x7FFFu + ((v.u >> 16) & 1u)) >> 16);
}
__device__ __forceinline__ float bf2f(unsigned short h) {
    union { unsigned u; float f; } v; v.u = ((unsigned)h) << 16; return v.f;
}
__device__ __forceinline__ short8 pack8(const float4& a, const float4& b) {
    short8 r;
    r[0] = (short)f2bf(a.x); r[1] = (short)f2bf(a.y);
    r[2] = (short)f2bf(a.z); r[3] = (short)f2bf(a.w);
    r[4] = (short)f2bf(b.x); r[5] = (short)f2bf(b.y);
    r[6] = (short)f2bf(b.z); r[7] = (short)f2bf(b.w);
    return r;
}

// async coalesced stage: per-lane 16B contiguous global src -> linear LDS (lane*16)
#define GLOAD_LDS16(gp, lp)                                                     \
    __builtin_amdgcn_global_load_lds(                                           \
        (const __attribute__((address_space(1))) unsigned int*)(const void*)(gp), \
        (__attribute__((address_space(3))) unsigned int*)(void*)(lp), 16, 0, 0)

// stage chunk ch (32 c-rows x 64 px fp32 = 8 KB) into slab[ch&3]; 2 instrs/wave.
// instr (w,i): dest dw [w*512+i*256, +256); lane l -> c_local = w*8+i*4+(l>>4),
// px-group = l&15, SOURCE px-group pre-swizzled g' = (g + 2w)&15 so the
// transposed read below is <=2-way bank-conflict (store/read same involution).
#define ISSUEC(ch) {                                                            \
    _Pragma("unroll")                                                           \
    for (int _i = 0; _i < 2; ++_i) {                                            \
        const int _cl = w * 8 + _i * 4 + (lane >> 4);                           \
        const float* _src = xb + (size_t)((ch) * 32 + _cl) * NPIX + pxs;        \
        GLOAD_LDS16(_src, &slab[(ch) & 3][w * 512 + _i * 256]);                 \
    } }

// ---------------------------------------------------------------------------
// kA: per (64-px split, batch): A[k][px] = softmax_k(scale_k*(xsq+csq_k-2 x.c_k))
//  - x staged COALESCED via global_load_lds width=16 (4x256B contiguous per
//    instr) into a block-shared transposed slab [32c][64px], 4 buffers.
//  - 3-chunk prefetch lead, counted s_waitcnt vmcnt(4) (never 0 until tail),
//    raw s_barrier (no vmcnt drain). ISSUE(ch+3) after the barrier so the
//    overwritten buffer (ch-1) is dead.
//  - read side: 8x ds_read_b32 at swizzled offsets -> <=2-way conflict (free).
//  - cw staged once to LDS bf16 (cs, lgkmcnt only -> vmcnt counting stays clean).
// ---------------------------------------------------------------------------
__global__ __launch_bounds__(256, 2) void kA(const float* __restrict__ x,
                                             const float* __restrict__ cw,
                                             const float* __restrict__ scale,
                                             unsigned short* __restrict__ Ag)
{
    __shared__ __align__(16) unsigned short cs[KK * CW_S];   // 33280 B
    __shared__ __align__(16) float slab[4][32 * 64];         // 32768 B
    __shared__ float csq_p[8][KK];
    __shared__ float csq_l[KK];
    __shared__ float wredA[4][KK];

    const int t    = threadIdx.x;
    const int lane = t & 63, w = t >> 6;
    const int col  = lane & 15, quad = lane >> 4;
    const int split = blockIdx.x, b = blockIdx.y;
    const int p0    = (split < 12) ? split * 64 : 720;   // split 12 overlaps by 48 px

    // ---- zero A pad region n in [784,800) once per batch (idempotent) ----
    if (split == 0 && t < 64) {
        const short8 z = {0, 0, 0, 0, 0, 0, 0, 0};
        const int k = t >> 1, off = (t & 1) * 8;
        *(short8*)&Ag[(size_t)b * KK * AS + (size_t)k * AS + NPIX + off] = z;
    }

    // ---- stage cw -> bf16 LDS ----
#pragma unroll 4
    for (int j = 0; j < 16; ++j) {
        const int qidx = t + j * 256;
        const int row = qidx >> 7, qc = qidx & 127;
        const float4 v = *(const float4*)&cw[row * CC + qc * 4];
        ushort4v p; p.x = f2bf(v.x); p.y = f2bf(v.y); p.z = f2bf(v.z); p.w = f2bf(v.w);
        *(ushort4v*)&cs[row * CW_S + qc * 4] = p;
    }
    __syncthreads();
    // ---- csq ----
    {
        const int k = t & 31, part = t >> 5;
        float s = 0.f;
        for (int i = 0; i < 64; ++i) {
            const float v = bf2f(cs[k * CW_S + part * 64 + i]);
            s += v * v;
        }
        csq_p[part][k] = s;
    }
    __syncthreads();
    if (t < KK) {
        float s = 0.f;
#pragma unroll
        for (int p = 0; p < 8; ++p) s += csq_p[p][t];
        csq_l[t] = s;
    }
    __syncthreads();   // drains vmcnt to 0: clean baseline for counted waits

    const float s0 = scale[col], s1 = scale[col + 16];
    const float q0 = csq_l[col], q1 = csq_l[col + 16];

    const float* xb = x + (size_t)b * CC * NPIX + p0;
    const int pxs  = 4 * (((lane & 15) + 2 * w) & 15);      // swizzled source px
    const int roff = (w * 16 + col + 8 * quad) & 63;        // swizzled read px offset

    floatx4 acc0 = {0.f, 0.f, 0.f, 0.f};
    floatx4 acc1 = {0.f, 0.f, 0.f, 0.f};
    float xsqp = 0.f;

    // ---- main loop: 16 chunks of 32 c; 4-buffer, 3-chunk prefetch lead ----
    ISSUEC(0); ISSUEC(1); ISSUEC(2);
#pragma unroll
    for (int ch = 0; ch < 16; ++ch) {
        if (ch <= 13)      asm volatile("s_waitcnt vmcnt(4)" ::: "memory");
        else if (ch == 14) asm volatile("s_waitcnt vmcnt(2)" ::: "memory");
        else               asm volatile("s_waitcnt vmcnt(0)" ::: "memory");
        __builtin_amdgcn_s_barrier();
        __builtin_amdgcn_sched_barrier(0);
        if (ch + 3 < 16) ISSUEC(ch + 3);   // overwrites buf of ch-1: dead post-barrier
        // compute chunk ch (one kc-step of 32 channels)
        float va[8];
#pragma unroll
        for (int j = 0; j < 8; ++j) va[j] = slab[ch & 3][(quad * 8 + j) * 64 + roff];
        short8 a;
#pragma unroll
        for (int j = 0; j < 8; ++j) { xsqp += va[j] * va[j]; a[j] = (short)f2bf(va[j]); }
        const int cb = ch * 32 + quad * 8;
        const short8 b0 = *(const short8*)&cs[col * CW_S + cb];
        const short8 b1 = *(const short8*)&cs[(col + 16) * CW_S + cb];
        acc0 = __builtin_amdgcn_mfma_f32_16x16x32_bf16(a, b0, acc0, 0, 0, 0);
        acc1 = __builtin_amdgcn_mfma_f32_16x16x32_bf16(a, b1, acc1, 0, 0, 0);
    }

    // xsq: sum quad slices -> every lane has xsq for its col's px
    xsqp += __shfl_xor(xsqp, 16);
    xsqp += __shfl_xor(xsqp, 32);

    // fused softmax epilogue; D row = px = quad*4+r, col = k
    unsigned short* Ab = Ag + (size_t)b * KK * AS + p0 + w * 16;
    float ts0 = 0.f, ts1 = 0.f;   // per-lane partial wsum over this tile
#pragma unroll
    for (int r = 0; r < 4; ++r) {
        const float xq = __shfl(xsqp, quad * 4 + r);   // lane (quad*4+r) holds that px's xsq
        const float d0 = s0 * (xq + q0 - 2.f * acc0[r]);
        const float d1 = s1 * (xq + q1 - 2.f * acc1[r]);
        float mx = fmaxf(d0, d1);
        mx = fmaxf(mx, __shfl_xor(mx, 1));
        mx = fmaxf(mx, __shfl_xor(mx, 2));
        mx = fmaxf(mx, __shfl_xor(mx, 4));
        mx = fmaxf(mx, __shfl_xor(mx, 8));
        const float e0 = __expf(d0 - mx), e1 = __expf(d1 - mx);
        float sm = e0 + e1;
        sm += __shfl_xor(sm, 1);
        sm += __shfl_xor(sm, 2);
        sm += __shfl_xor(sm, 4);
        sm += __shfl_xor(sm, 8);
        const float inv = 1.f / sm;
        const float a0 = e0 * inv, a1 = e1 * inv;
        Ab[col * AS + quad * 4 + r]        = f2bf(a0);
        Ab[(col + 16) * AS + quad * 4 + r] = f2bf(a1);
        ts0 += a0; ts1 += a1;
    }

    // per-tile wsum: reduce over the 4 quads (16 px of this tile)
    ts0 += __shfl_xor(ts0, 16); ts0 += __shfl_xor(ts0, 32);
    ts1 += __shfl_xor(ts1, 16); ts1 += __shfl_xor(ts1, 32);
    if (quad == 0) { wredA[w][col] = ts0; wredA[w][col + 16] = ts1; }
    __syncthreads();
    if (t < KK) {
        // split 12: tiles w=0..2 duplicate split 11's coverage -> count only w=3
        float s;
        if (split < 12) s = wredA[0][t] + wredA[1][t] + wredA[2][t] + wredA[3][t];
        else            s = wredA[3][t];
        float* wsf = (float*)(Ag + WSUM_OFF);
        wsf[(size_t)(split * BB + b) * KK + t] = s;
    }
}

// ---------------------------------------------------------------------------
// kB: per (c-chunk of 64, batch): out[k][c] = sum_n A[k][n] x[c][n] - wsum_k cw[k][c]
//  - barrier-free main loop, A (L2-hot) and x (L3-hot from kA) direct from global
//  - wsum from kA's per-split partials (13 adds per k)
// ---------------------------------------------------------------------------
__global__ __launch_bounds__(256) void kB(const float* __restrict__ x,
                                          const float* __restrict__ cw,
                                          const unsigned short* __restrict__ Ag,
                                          float* __restrict__ out)
{
    __shared__ float wsum_l[KK];

    const int t    = threadIdx.x;
    const int lane = t & 63, w = t >> 6;
    const int col  = lane & 15, quad = lane >> 4;
    const int cch  = blockIdx.x, b = blockIdx.y;

    const unsigned short* Ab = Ag + (size_t)b * KK * AS;

    // ---- wsum: sum kA's 13 per-split partials ----
    if (t < KK) {
        const float* wsf = (const float*)(Ag + WSUM_OFF);
        float s = 0.f;
#pragma unroll
        for (int sp = 0; sp < NSA; ++sp) s += wsf[(size_t)(sp * BB + b) * KK + t];
        wsum_l[t] = s;
    }

    // ---- main GEMM: this wave owns 16 c-rows; contract n = 0..800 ----
    const int c = cch * 64 + w * 16 + col;
    const float* xp = x + ((size_t)b * CC + c) * NPIX;
    const unsigned short* a0p = Ab + (size_t)col * AS;
    const unsigned short* a1p = Ab + (size_t)(col + 16) * AS;
    const int qo = quad * 8;

    floatx4 acc0 = {0.f, 0.f, 0.f, 0.f};
    floatx4 acc1 = {0.f, 0.f, 0.f, 0.f};
#pragma unroll 6
    for (int s = 0; s < NSTEP; ++s) {
        const int off = s * 32 + qo;
        const short8 av0 = *(const short8*)&a0p[off];
        const short8 av1 = *(const short8*)&a1p[off];
        const float4 xv0 = *(const float4*)&xp[off];
        const float4 xv1 = *(const float4*)&xp[off + 4];
        const short8 bv = pack8(xv0, xv1);
        acc0 = __builtin_amdgcn_mfma_f32_16x16x32_bf16(av0, bv, acc0, 0, 0, 0);
        acc1 = __builtin_amdgcn_mfma_f32_16x16x32_bf16(av1, bv, acc1, 0, 0, 0);
    }
    {   // tail step: n in [768,800); x rows end at 784 -> predicate quads 2,3 (A pad is zero)
        const int off = NSTEP * 32 + qo;
        const short8 av0 = *(const short8*)&a0p[off];
        const short8 av1 = *(const short8*)&a1p[off];
        float4 xv0 = make_float4(0.f, 0.f, 0.f, 0.f);
        float4 xv1 = make_float4(0.f, 0.f, 0.f, 0.f);
        if (quad < 2) {
            xv0 = *(const float4*)&xp[off];
            xv1 = *(const float4*)&xp[off + 4];
        }
        const short8 bv = pack8(xv0, xv1);
        acc0 = __builtin_amdgcn_mfma_f32_16x16x32_bf16(av0, bv, acc0, 0, 0, 0);
        acc1 = __builtin_amdgcn_mfma_f32_16x16x32_bf16(av1, bv, acc1, 0, 0, 0);
    }

    __syncthreads();   // wsum_l ready

    // ---- fused epilogue: out = W - wsum*cw ----
    float* ob = out + (size_t)b * KK * CC + c;
    const float* cp = cw + c;
#pragma unroll
    for (int r = 0; r < 4; ++r) {
        const int k0 = quad * 4 + r;
        ob[(size_t)k0 * CC]        = acc0[r] - wsum_l[k0]      * cp[(size_t)k0 * CC];
        ob[(size_t)(k0 + 16) * CC] = acc1[r] - wsum_l[k0 + 16] * cp[(size_t)(k0 + 16) * CC];
    }
}

extern "C" void kernel_launch(void* const* d_in, const int* in_sizes, int n_in,
                              void* d_out, int out_size, void* d_ws, size_t ws_size,
                              hipStream_t stream) {
    const float* x     = (const float*)d_in[0];   // (64, 512, 28, 28)
    const float* cw    = (const float*)d_in[1];   // (32, 512)
    const float* scale = (const float*)d_in[2];   // (32,)
    float* out = (float*)d_out;                   // (64, 32, 512)
    unsigned short* Ag = (unsigned short*)d_ws;   // A bf16 [64][32][800] + wsum_p f32 [13][64][32]

    kA<<<dim3(NSA, BB), dim3(256), 0, stream>>>(x, cw, scale, Ag);
    kB<<<dim3(8, BB), dim3(256), 0, stream>>>(x, cw, Ag, out);
}